// Round 13
// baseline (236.246 us; speedup 1.0000x reference)
//
#include <hip/hip_runtime.h>
#include <hip/hip_bf16.h>

#define NB 2
#define NN 20000
#define NKN 16          // neighbors per node
#define NC 128          // C_IN
#define NM 9            // M kernels
#define NO 128          // C_OUT
#define NR (NB*NN)      // 40000 rows
#define KK (NM*NC)      // 1152 GEMM reduce dim
#define NKC (KK/32)     // 36 K-chunks of 32
#define NPB 16          // nodes per tile
#define NTL 2           // tiles per block (software pipelined)
#define YS 12           // padded y row stride (floats)
#define YB (NR/64)      // ycalc blocks = 625

typedef short bf16x8 __attribute__((ext_vector_type(8)));
typedef float f32x4 __attribute__((ext_vector_type(4)));
typedef float f32x2 __attribute__((ext_vector_type(2)));
typedef unsigned short u16x8 __attribute__((ext_vector_type(8)));

__device__ inline f32x2 bfpair(unsigned int w) {   // [lo16, hi16] bf16 -> float2
    union { unsigned int u; float f; } lo, hi;
    lo.u = w << 16; hi.u = w & 0xFFFF0000u;
    return (f32x2){lo.f, hi.f};
}

// ---------------- Kernel 1: prep (R9-R11 version, unchanged) ----------------
__global__ __launch_bounds__(256) void prep_kernel(const float* __restrict__ x,
                                                   const float* __restrict__ u,
                                                   const float* __restrict__ W,
                                                   float* __restrict__ y,
                                                   __hip_bfloat16* __restrict__ xb,
                                                   __hip_bfloat16* __restrict__ Wg,
                                                   int use_xb) {
    int tid = threadIdx.x;
    if (blockIdx.x < YB) {
        int wave = tid >> 6, lane = tid & 63;
        int lr = lane & 15, quad = lane >> 4;
        int node0 = blockIdx.x * 64 + wave * 16;
        long xbase = (long)(node0 + lr) * NC;

        bf16x8 afr[4];
        #pragma unroll
        for (int kc = 0; kc < 4; kc++) {
            const float* px = x + xbase + kc * 32 + quad * 8;
            float4 a0 = *(const float4*)px;
            float4 a1 = *(const float4*)(px + 4);
            union { bf16x8 v; unsigned short s[8]; __hip_bfloat16 h[8]; } af;
            af.h[0] = __float2bfloat16(a0.x); af.h[1] = __float2bfloat16(a0.y);
            af.h[2] = __float2bfloat16(a0.z); af.h[3] = __float2bfloat16(a0.w);
            af.h[4] = __float2bfloat16(a1.x); af.h[5] = __float2bfloat16(a1.y);
            af.h[6] = __float2bfloat16(a1.z); af.h[7] = __float2bfloat16(a1.w);
            afr[kc] = af.v;
            if (use_xb)
                *(u16x8*)((unsigned short*)xb + xbase + kc * 32 + quad * 8) =
                    *(u16x8*)&af.v;
        }
        int cs = (lr < NM) ? lr : 0;
        float fz = (lr < NM) ? 1.f : 0.f;
        f32x4 acc = (f32x4){0.f, 0.f, 0.f, 0.f};
        #pragma unroll
        for (int kc = 0; kc < 4; kc++) {
            const float* pu = u + cs * NC + kc * 32 + quad * 8;
            float4 b0 = *(const float4*)pu;
            float4 b1 = *(const float4*)(pu + 4);
            union { bf16x8 v; __hip_bfloat16 h[8]; } bf;
            bf.h[0] = __float2bfloat16(b0.x * fz); bf.h[1] = __float2bfloat16(b0.y * fz);
            bf.h[2] = __float2bfloat16(b0.z * fz); bf.h[3] = __float2bfloat16(b0.w * fz);
            bf.h[4] = __float2bfloat16(b1.x * fz); bf.h[5] = __float2bfloat16(b1.y * fz);
            bf.h[6] = __float2bfloat16(b1.z * fz); bf.h[7] = __float2bfloat16(b1.w * fz);
            acc = __builtin_amdgcn_mfma_f32_16x16x32_bf16(afr[kc], bf.v, acc, 0, 0, 0);
        }
        if (lr < NM) {
            #pragma unroll
            for (int r = 0; r < 4; r++)
                y[(long)(node0 + quad * 4 + r) * YS + lr] = acc[r];
        }
    } else {
        int t = (blockIdx.x - YB) * 256 + tid;   // t < 9*128*128
        int c = t & 127;
        int o = (t >> 7) & 127;
        int m = t >> 14;
        int kk = m * 128 + c;
        float v = W[m * 16384 + o * 128 + c];
        Wg[((kk >> 5) * 128 + o) * 32 + (kk & 31)] = __float2bfloat16(v);
    }
}

// ---------------- Kernel 2: fused, 2-tile software pipeline ----------------
// Block = 2 tiles x 16 nodes, 256 threads, LDS 36,864 B -> 4 blocks/CU.
// Tile datapath = R11 (q-in-S'-row overlay, __expf, di-folded q, XOR swizzles).
// Pipeline: tile1's adj + batch-0 gathers issue BEFORE bar3 and fly under
// phase B(0); tile1's y/ya loads (assign-only macro, vars at fn scope) issue
// under B(0)'s epilogue. All prefetch lands in REGISTERS.
// Barriers: bar3 S'(0) ready / bar4 S' free / bar5 S'(1) ready.
template<bool BF16G>
__global__ __launch_bounds__(256, 4) void fused_kernel(const float* __restrict__ x,
                                                       const __hip_bfloat16* __restrict__ xb,
                                                       const int* __restrict__ adj,
                                                       const float* __restrict__ y,
                                                       const float* __restrict__ cv,
                                                       const __hip_bfloat16* __restrict__ Wg,
                                                       const float* __restrict__ bv,
                                                       float* __restrict__ out) {
    __shared__ __align__(16) short s_S[NPB * KK];          // 36,864 B total LDS

    int tid = threadIdx.x;
    int tbase = blockIdx.x * (NPB * NTL);
    int ln = tid >> 4, k = tid & 15;                       // 256 = 16 nodes x 16 edges
    int c8 = k << 3;

    // node ln's q lives in its own S' row (R11 overlay)
    float* qb_ = (float*)((char*)s_S + ln * (KK * 2) + ((ln & 7) << 4));

    // ---------------- per-tile building blocks ----------------
    #define DECL_TILE(S) \
        int node0_##S = tbase + (S) * NPB; \
        int b_##S = node0_##S / NN; \
        int n0_##S = node0_##S - b_##S * NN;

    #define PUTV(S, ARR, J, V) \
        { int aa = (V); d_##S += (aa > 0); ARR##_##S[J] = (aa > 0) ? aa - 1 : 0; }

    // adj row + idx/deg + batch-0 gather issue (registers only)
    #define A_EARLY(S) \
        const int* arow_##S = adj + (n0_##S + ln) * NKN; \
        int a_##S = arow_##S[k]; \
        int4 r0_##S = *(const int4*)arow_##S; \
        int4 r1_##S = *(const int4*)(arow_##S + 4); \
        int4 r2_##S = *(const int4*)(arow_##S + 8); \
        int4 r3_##S = *(const int4*)(arow_##S + 12); \
        int idxl_##S[8], idxh_##S[8]; int d_##S = 0; \
        PUTV(S, idxl, 0, r0_##S.x) PUTV(S, idxl, 1, r0_##S.y) \
        PUTV(S, idxl, 2, r0_##S.z) PUTV(S, idxl, 3, r0_##S.w) \
        PUTV(S, idxl, 4, r1_##S.x) PUTV(S, idxl, 5, r1_##S.y) \
        PUTV(S, idxl, 6, r1_##S.z) PUTV(S, idxl, 7, r1_##S.w) \
        PUTV(S, idxh, 0, r2_##S.x) PUTV(S, idxh, 1, r2_##S.y) \
        PUTV(S, idxh, 2, r2_##S.z) PUTV(S, idxh, 3, r2_##S.w) \
        PUTV(S, idxh, 4, r3_##S.x) PUTV(S, idxh, 5, r3_##S.y) \
        PUTV(S, idxh, 6, r3_##S.z) PUTV(S, idxh, 7, r3_##S.w) \
        float di_##S = (d_##S > 0) ? 1.f / (float)d_##S : 0.f; \
        uint4 pw0_##S[8]; \
        if (BF16G) { \
            const unsigned short* xbs_ = (const unsigned short*)xb; \
            long rb_ = (long)b_##S * NN; \
            pw0_##S[0] = *(const uint4*)(xbs_ + (rb_ + idxl_##S[0]) * NC + c8); \
            pw0_##S[1] = *(const uint4*)(xbs_ + (rb_ + idxl_##S[1]) * NC + c8); \
            pw0_##S[2] = *(const uint4*)(xbs_ + (rb_ + idxl_##S[2]) * NC + c8); \
            pw0_##S[3] = *(const uint4*)(xbs_ + (rb_ + idxl_##S[3]) * NC + c8); \
            pw0_##S[4] = *(const uint4*)(xbs_ + (rb_ + idxl_##S[4]) * NC + c8); \
            pw0_##S[5] = *(const uint4*)(xbs_ + (rb_ + idxl_##S[5]) * NC + c8); \
            pw0_##S[6] = *(const uint4*)(xbs_ + (rb_ + idxl_##S[6]) * NC + c8); \
            pw0_##S[7] = *(const uint4*)(xbs_ + (rb_ + idxl_##S[7]) * NC + c8); \
        }

    // declarations (function scope) and assignment-only loads, separated so a
    // load can be issued inside a nested block (R12 compile-fix).
    #define Y_DECL(S) \
        float4 yn0_##S, yn1_##S, ya0_##S, ya1_##S; \
        float yn8_##S, ya8_##S;

    #define Y_LOAD(S) { \
        const float* ynp = y + (long)(node0_##S + ln) * YS; \
        const float* yap = y + ((long)b_##S * NN + ((a_##S > 0) ? a_##S - 1 : 0)) * YS; \
        yn0_##S = *(const float4*)ynp; \
        yn1_##S = *(const float4*)(ynp + 4); \
        yn8_##S = ynp[8]; \
        ya0_##S = *(const float4*)yap; \
        ya1_##S = *(const float4*)(yap + 4); \
        ya8_##S = yap[8]; \
    }

    // softmax -> q' (softmax * deg_inv) into own S' row; then intra-wave fence
    #define SOFTMAX_Q(S) { \
        float sel = (a_##S > 0) ? 1.f : 0.f; \
        float l[NM]; \
        l[0] = yn0_##S.x - sel * ya0_##S.x + cv[0]; \
        l[1] = yn0_##S.y - sel * ya0_##S.y + cv[1]; \
        l[2] = yn0_##S.z - sel * ya0_##S.z + cv[2]; \
        l[3] = yn0_##S.w - sel * ya0_##S.w + cv[3]; \
        l[4] = yn1_##S.x - sel * ya1_##S.x + cv[4]; \
        l[5] = yn1_##S.y - sel * ya1_##S.y + cv[5]; \
        l[6] = yn1_##S.z - sel * ya1_##S.z + cv[6]; \
        l[7] = yn1_##S.w - sel * ya1_##S.w + cv[7]; \
        l[8] = yn8_##S   - sel * ya8_##S   + cv[8]; \
        float mx = l[0]; \
        _Pragma("unroll") \
        for (int m = 1; m < NM; m++) mx = fmaxf(mx, l[m]); \
        float e[NM]; float sum = 0.f; \
        _Pragma("unroll") \
        for (int m = 0; m < NM; m++) { e[m] = __expf(l[m] - mx); sum += e[m]; } \
        float qs = ((a_##S > 0) ? (1.f / sum) : 0.f) * di_##S; \
        _Pragma("unroll") \
        for (int m = 0; m < NM; m++) qb_[k * 12 + m] = e[m] * qs; \
    } \
    asm volatile("s_waitcnt lgkmcnt(0)" ::: "memory"); \
    __builtin_amdgcn_sched_barrier(0);

    #define ACC_ALL(P0, P1, P2, P3, KK2) {                                    \
        const float* qr = qb_ + (KK2) * 12;                                   \
        float4 qa = *(const float4*)qr;                                       \
        float4 qb = *(const float4*)(qr + 4);                                 \
        float  q8 = qr[8];                                                    \
        f32x2 qq;                                                             \
        qq=(f32x2){qa.x,qa.x}; s2[0][0]+=qq*P0; s2[0][1]+=qq*P1; s2[0][2]+=qq*P2; s2[0][3]+=qq*P3; \
        qq=(f32x2){qa.y,qa.y}; s2[1][0]+=qq*P0; s2[1][1]+=qq*P1; s2[1][2]+=qq*P2; s2[1][3]+=qq*P3; \
        qq=(f32x2){qa.z,qa.z}; s2[2][0]+=qq*P0; s2[2][1]+=qq*P1; s2[2][2]+=qq*P2; s2[2][3]+=qq*P3; \
        qq=(f32x2){qa.w,qa.w}; s2[3][0]+=qq*P0; s2[3][1]+=qq*P1; s2[3][2]+=qq*P2; s2[3][3]+=qq*P3; \
        qq=(f32x2){qb.x,qb.x}; s2[4][0]+=qq*P0; s2[4][1]+=qq*P1; s2[4][2]+=qq*P2; s2[4][3]+=qq*P3; \
        qq=(f32x2){qb.y,qb.y}; s2[5][0]+=qq*P0; s2[5][1]+=qq*P1; s2[5][2]+=qq*P2; s2[5][3]+=qq*P3; \
        qq=(f32x2){qb.z,qb.z}; s2[6][0]+=qq*P0; s2[6][1]+=qq*P1; s2[6][2]+=qq*P2; s2[6][3]+=qq*P3; \
        qq=(f32x2){qb.w,qb.w}; s2[7][0]+=qq*P0; s2[7][1]+=qq*P1; s2[7][2]+=qq*P2; s2[7][3]+=qq*P3; \
        qq=(f32x2){q8,q8};     s2[8][0]+=qq*P0; s2[8][1]+=qq*P1; s2[8][2]+=qq*P2; s2[8][3]+=qq*P3; }

    // zero s2, batch-1 gather issue, 16 ACC_ALLs, S' pack (R11 layout)
    #define ACC_PACK(S) { \
        _Pragma("unroll") \
        for (int m = 0; m < NM; m++) { \
            _Pragma("unroll") \
            for (int j = 0; j < 4; j++) s2[m][j] = (f32x2){0.f, 0.f}; \
        } \
        if (BF16G) { \
            const unsigned short* xbs_ = (const unsigned short*)xb; \
            long rb_ = (long)b_##S * NN; \
            uint4 pw1[8]; \
            pw1[0] = *(const uint4*)(xbs_ + (rb_ + idxh_##S[0]) * NC + c8); \
            pw1[1] = *(const uint4*)(xbs_ + (rb_ + idxh_##S[1]) * NC + c8); \
            pw1[2] = *(const uint4*)(xbs_ + (rb_ + idxh_##S[2]) * NC + c8); \
            pw1[3] = *(const uint4*)(xbs_ + (rb_ + idxh_##S[3]) * NC + c8); \
            pw1[4] = *(const uint4*)(xbs_ + (rb_ + idxh_##S[4]) * NC + c8); \
            pw1[5] = *(const uint4*)(xbs_ + (rb_ + idxh_##S[5]) * NC + c8); \
            pw1[6] = *(const uint4*)(xbs_ + (rb_ + idxh_##S[6]) * NC + c8); \
            pw1[7] = *(const uint4*)(xbs_ + (rb_ + idxh_##S[7]) * NC + c8); \
            _Pragma("unroll") \
            for (int j = 0; j < 8; j++) { \
                f32x2 p0 = bfpair(pw0_##S[j].x), p1 = bfpair(pw0_##S[j].y); \
                f32x2 p2 = bfpair(pw0_##S[j].z), p3 = bfpair(pw0_##S[j].w); \
                ACC_ALL(p0, p1, p2, p3, j) \
            } \
            _Pragma("unroll") \
            for (int j = 0; j < 8; j++) { \
                f32x2 p0 = bfpair(pw1[j].x), p1 = bfpair(pw1[j].y); \
                f32x2 p2 = bfpair(pw1[j].z), p3 = bfpair(pw1[j].w); \
                ACC_ALL(p0, p1, p2, p3, 8 + j) \
            } \
        } else { \
            long rb_ = (long)b_##S * NN; \
            _Pragma("unroll") \
            for (int j = 0; j < 8; j++) { \
                const float* px = x + (rb_ + idxl_##S[j]) * NC + c8; \
                float4 fa = *(const float4*)px; \
                float4 fb = *(const float4*)(px + 4); \
                f32x2 p0 = (f32x2){fa.x, fa.y}, p1 = (f32x2){fa.z, fa.w}; \
                f32x2 p2 = (f32x2){fb.x, fb.y}, p3 = (f32x2){fb.z, fb.w}; \
                ACC_ALL(p0, p1, p2, p3, j) \
            } \
            _Pragma("unroll") \
            for (int j = 0; j < 8; j++) { \
                const float* px = x + (rb_ + idxh_##S[j]) * NC + c8; \
                float4 fa = *(const float4*)px; \
                float4 fb = *(const float4*)(px + 4); \
                f32x2 p0 = (f32x2){fa.x, fa.y}, p1 = (f32x2){fa.z, fa.w}; \
                f32x2 p2 = (f32x2){fb.x, fb.y}, p3 = (f32x2){fb.z, fb.w}; \
                ACC_ALL(p0, p1, p2, p3, 8 + j) \
            } \
        } \
        _Pragma("unroll") \
        for (int m = 0; m < NM; m++) { \
            u16x8 ov; \
            _Pragma("unroll") \
            for (int j = 0; j < 4; j++) { \
                union { unsigned short h; __hip_bfloat16 bb; } c0_, c1_; \
                c0_.bb = __float2bfloat16(s2[m][j][0]); \
                c1_.bb = __float2bfloat16(s2[m][j][1]); \
                ov[j * 2]     = c0_.h; \
                ov[j * 2 + 1] = c1_.h; \
            } \
            int g = m * 16 + k; \
            int gs = g ^ (ln & 7); \
            *(u16x8*)(&s_S[ln * KK + gs * 8]) = ov; \
        } \
    }

    // phase B (R11 verbatim; kc=0 uses prefetched pf0/pf1); __VA_ARGS__ runs
    // between the kc-loop and the epilogue (used to issue tile1's y loads).
    #define B_PHASE(S, ...) { \
        f32x4 acc0 = (f32x4){0.f, 0.f, 0.f, 0.f}; \
        f32x4 acc1 = (f32x4){0.f, 0.f, 0.f, 0.f}; \
        { \
            int gs = quad ^ (lr & 7); \
            bf16x8 a0 = *(const bf16x8*)(&s_S[lr * KK + gs * 8]); \
            acc0 = __builtin_amdgcn_mfma_f32_16x16x32_bf16(a0, pf0, acc0, 0, 0, 0); \
            acc1 = __builtin_amdgcn_mfma_f32_16x16x32_bf16(a0, pf1, acc1, 0, 0, 0); \
        } \
        _Pragma("unroll 7") \
        for (int kc = 1; kc < NKC; kc++) { \
            int g = kc * 4 + quad; \
            int gs = g ^ (lr & 7); \
            bf16x8 a0 = *(const bf16x8*)(&s_S[lr * KK + gs * 8]); \
            bf16x8 bf0 = *(const bf16x8*)(wg + ((kc * 128) + wave * 16 + lr) * 32 + quad * 8); \
            bf16x8 bf1 = *(const bf16x8*)(wg + ((kc * 128) + (wave + 4) * 16 + lr) * 32 + quad * 8); \
            acc0 = __builtin_amdgcn_mfma_f32_16x16x32_bf16(a0, bf0, acc0, 0, 0, 0); \
            acc1 = __builtin_amdgcn_mfma_f32_16x16x32_bf16(a0, bf1, acc1, 0, 0, 0); \
        } \
        __VA_ARGS__ \
        int rbase = node0_##S + quad * 4; \
        _Pragma("unroll") \
        for (int r = 0; r < 4; r++) { \
            out[(long)(rbase + r) * NO + col0] = acc0[r] + bb0; \
            out[(long)(rbase + r) * NO + col1] = acc1[r] + bb1; \
        } \
    }

    // ---------------- pipeline ----------------
    DECL_TILE(0)
    DECL_TILE(1)
    f32x2 s2[NM][4];

    // tile 0 front end
    A_EARLY(0)
    Y_DECL(0)
    Y_LOAD(0)
    SOFTMAX_Q(0)
    ACC_PACK(0)

    // tile 1 front end issue (registers only; flies under bar3 + B(0))
    A_EARLY(1)
    Y_DECL(1)

    // tile-invariant phase-B prefetch
    int wave = tid >> 6;
    int lane = tid & 63;
    int lr = lane & 15;
    int quad = lane >> 4;
    const short* wg = reinterpret_cast<const short*>(Wg);
    int col0 = wave * 16 + lr;
    int col1 = col0 + 64;
    float bb0 = bv[col0];
    float bb1 = bv[col1];
    bf16x8 pf0 = *(const bf16x8*)(wg + (wave * 16 + lr) * 32 + quad * 8);
    bf16x8 pf1 = *(const bf16x8*)(wg + ((wave + 4) * 16 + lr) * 32 + quad * 8);

    __syncthreads();                                   // bar3: S'(0) ready

    B_PHASE(0, Y_LOAD(1))                              // y(1) issues under epilogue

    __syncthreads();                                   // bar4: B(0) done, S' free

    SOFTMAX_Q(1)
    ACC_PACK(1)

    __syncthreads();                                   // bar5: S'(1) ready

    B_PHASE(1, ;)

    #undef B_PHASE
    #undef ACC_PACK
    #undef ACC_ALL
    #undef SOFTMAX_Q
    #undef Y_LOAD
    #undef Y_DECL
    #undef A_EARLY
    #undef PUTV
    #undef DECL_TILE
}

extern "C" void kernel_launch(void* const* d_in, const int* in_sizes, int n_in,
                              void* d_out, int out_size, void* d_ws, size_t ws_size,
                              hipStream_t stream) {
    const float* x   = (const float*)d_in[0];   // (B,N,C)
    const int*   adj = (const int*)  d_in[1];   // (N,K)
    const float* W   = (const float*)d_in[2];   // (M,O,C)
    const float* bv  = (const float*)d_in[3];   // (O,)
    const float* u   = (const float*)d_in[4];   // (M,C)
    const float* cv  = (const float*)d_in[5];   // (M,)
    float* out = (float*)d_out;

    char* ws = (char*)d_ws;
    float* y = (float*)ws;                                     // 1,920,000 B
    __hip_bfloat16* Wg = (__hip_bfloat16*)(ws + 1920000);      //   294,912 B
    __hip_bfloat16* xb = (__hip_bfloat16*)(ws + 2214912);      // 10,240,000 B
    bool use_xb = (ws_size >= (size_t)12454912);

    prep_kernel<<<YB + 576, 256, 0, stream>>>(x, u, W, y, use_xb ? xb : nullptr, Wg,
                                              use_xb ? 1 : 0);
    if (use_xb)
        fused_kernel<true><<<NR / (NPB * NTL), 256, 0, stream>>>(x, xb, adj, y, cv, Wg, bv, out);
    else
        fused_kernel<false><<<NR / (NPB * NTL), 256, 0, stream>>>(x, xb, adj, y, cv, Wg, bv, out);
}

// Round 14
// 146.847 us; speedup vs baseline: 1.6088x; 1.6088x over previous
//
#include <hip/hip_runtime.h>
#include <hip/hip_bf16.h>

#define NB 2
#define NN 20000
#define NKN 16          // neighbors per node
#define NC 128          // C_IN
#define NM 9            // M kernels
#define NO 128          // C_OUT
#define NR (NB*NN)      // 40000 rows
#define KK (NM*NC)      // 1152 GEMM reduce dim
#define NKC (KK/32)     // 36 K-chunks of 32
#define NPB 16          // nodes per tile
#define NTL 2           // tiles per block (software pipelined)
#define YS 12           // padded y row stride (floats)
#define YB (NR/64)      // ycalc blocks = 625

typedef short bf16x8 __attribute__((ext_vector_type(8)));
typedef float f32x4 __attribute__((ext_vector_type(4)));
typedef float f32x2 __attribute__((ext_vector_type(2)));
typedef unsigned short u16x8 __attribute__((ext_vector_type(8)));

__device__ inline f32x2 bfpair(unsigned int w) {   // [lo16, hi16] bf16 -> float2
    union { unsigned int u; float f; } lo, hi;
    lo.u = w << 16; hi.u = w & 0xFFFF0000u;
    return (f32x2){lo.f, hi.f};
}

// ---------------- Kernel 1: prep (R9-R11 version, unchanged) ----------------
__global__ __launch_bounds__(256) void prep_kernel(const float* __restrict__ x,
                                                   const float* __restrict__ u,
                                                   const float* __restrict__ W,
                                                   float* __restrict__ y,
                                                   __hip_bfloat16* __restrict__ xb,
                                                   __hip_bfloat16* __restrict__ Wg,
                                                   int use_xb) {
    int tid = threadIdx.x;
    if (blockIdx.x < YB) {
        int wave = tid >> 6, lane = tid & 63;
        int lr = lane & 15, quad = lane >> 4;
        int node0 = blockIdx.x * 64 + wave * 16;
        long xbase = (long)(node0 + lr) * NC;

        bf16x8 afr[4];
        #pragma unroll
        for (int kc = 0; kc < 4; kc++) {
            const float* px = x + xbase + kc * 32 + quad * 8;
            float4 a0 = *(const float4*)px;
            float4 a1 = *(const float4*)(px + 4);
            union { bf16x8 v; unsigned short s[8]; __hip_bfloat16 h[8]; } af;
            af.h[0] = __float2bfloat16(a0.x); af.h[1] = __float2bfloat16(a0.y);
            af.h[2] = __float2bfloat16(a0.z); af.h[3] = __float2bfloat16(a0.w);
            af.h[4] = __float2bfloat16(a1.x); af.h[5] = __float2bfloat16(a1.y);
            af.h[6] = __float2bfloat16(a1.z); af.h[7] = __float2bfloat16(a1.w);
            afr[kc] = af.v;
            if (use_xb)
                *(u16x8*)((unsigned short*)xb + xbase + kc * 32 + quad * 8) =
                    *(u16x8*)&af.v;
        }
        int cs = (lr < NM) ? lr : 0;
        float fz = (lr < NM) ? 1.f : 0.f;
        f32x4 acc = (f32x4){0.f, 0.f, 0.f, 0.f};
        #pragma unroll
        for (int kc = 0; kc < 4; kc++) {
            const float* pu = u + cs * NC + kc * 32 + quad * 8;
            float4 b0 = *(const float4*)pu;
            float4 b1 = *(const float4*)(pu + 4);
            union { bf16x8 v; __hip_bfloat16 h[8]; } bf;
            bf.h[0] = __float2bfloat16(b0.x * fz); bf.h[1] = __float2bfloat16(b0.y * fz);
            bf.h[2] = __float2bfloat16(b0.z * fz); bf.h[3] = __float2bfloat16(b0.w * fz);
            bf.h[4] = __float2bfloat16(b1.x * fz); bf.h[5] = __float2bfloat16(b1.y * fz);
            bf.h[6] = __float2bfloat16(b1.z * fz); bf.h[7] = __float2bfloat16(b1.w * fz);
            acc = __builtin_amdgcn_mfma_f32_16x16x32_bf16(afr[kc], bf.v, acc, 0, 0, 0);
        }
        if (lr < NM) {
            #pragma unroll
            for (int r = 0; r < 4; r++)
                y[(long)(node0 + quad * 4 + r) * YS + lr] = acc[r];
        }
    } else {
        int t = (blockIdx.x - YB) * 256 + tid;   // t < 9*128*128
        int c = t & 127;
        int o = (t >> 7) & 127;
        int m = t >> 14;
        int kk = m * 128 + c;
        float v = W[m * 16384 + o * 128 + c];
        Wg[((kk >> 5) * 128 + o) * 32 + (kk & 31)] = __float2bfloat16(v);
    }
}

// ---------------- Kernel 2: fused, 2-tile software pipeline ----------------
// Block = 2 tiles x 16 nodes, 256 threads, LDS 36,864 B.
// R13 delta: __launch_bounds__(256, 2) — R13's (256,4) made the allocator pin
// arch-VGPRs at the 64 tier and spill tile-1's cross-barrier live set
// (264 MB scratch traffic). (256,2) licenses the ~100-140 regs the pipeline
// needs; the pipeline trades TLP for ILP by design.
// Pipeline: tile1's adj + batch-0 gathers issue BEFORE bar3 and fly under
// phase B(0); tile1's y/ya loads issue under B(0)'s epilogue. All prefetch
// lands in REGISTERS. Barriers: bar3 S'(0) ready / bar4 S' free / bar5 S'(1).
template<bool BF16G>
__global__ __launch_bounds__(256, 2) void fused_kernel(const float* __restrict__ x,
                                                       const __hip_bfloat16* __restrict__ xb,
                                                       const int* __restrict__ adj,
                                                       const float* __restrict__ y,
                                                       const float* __restrict__ cv,
                                                       const __hip_bfloat16* __restrict__ Wg,
                                                       const float* __restrict__ bv,
                                                       float* __restrict__ out) {
    __shared__ __align__(16) short s_S[NPB * KK];          // 36,864 B total LDS

    int tid = threadIdx.x;
    int tbase = blockIdx.x * (NPB * NTL);
    int ln = tid >> 4, k = tid & 15;                       // 256 = 16 nodes x 16 edges
    int c8 = k << 3;

    // node ln's q lives in its own S' row (R11 overlay)
    float* qb_ = (float*)((char*)s_S + ln * (KK * 2) + ((ln & 7) << 4));

    // ---------------- per-tile building blocks ----------------
    #define DECL_TILE(S) \
        int node0_##S = tbase + (S) * NPB; \
        int b_##S = node0_##S / NN; \
        int n0_##S = node0_##S - b_##S * NN;

    #define PUTV(S, ARR, J, V) \
        { int aa = (V); d_##S += (aa > 0); ARR##_##S[J] = (aa > 0) ? aa - 1 : 0; }

    // adj row + idx/deg + batch-0 gather issue (registers only)
    #define A_EARLY(S) \
        const int* arow_##S = adj + (n0_##S + ln) * NKN; \
        int a_##S = arow_##S[k]; \
        int4 r0_##S = *(const int4*)arow_##S; \
        int4 r1_##S = *(const int4*)(arow_##S + 4); \
        int4 r2_##S = *(const int4*)(arow_##S + 8); \
        int4 r3_##S = *(const int4*)(arow_##S + 12); \
        int idxl_##S[8], idxh_##S[8]; int d_##S = 0; \
        PUTV(S, idxl, 0, r0_##S.x) PUTV(S, idxl, 1, r0_##S.y) \
        PUTV(S, idxl, 2, r0_##S.z) PUTV(S, idxl, 3, r0_##S.w) \
        PUTV(S, idxl, 4, r1_##S.x) PUTV(S, idxl, 5, r1_##S.y) \
        PUTV(S, idxl, 6, r1_##S.z) PUTV(S, idxl, 7, r1_##S.w) \
        PUTV(S, idxh, 0, r2_##S.x) PUTV(S, idxh, 1, r2_##S.y) \
        PUTV(S, idxh, 2, r2_##S.z) PUTV(S, idxh, 3, r2_##S.w) \
        PUTV(S, idxh, 4, r3_##S.x) PUTV(S, idxh, 5, r3_##S.y) \
        PUTV(S, idxh, 6, r3_##S.z) PUTV(S, idxh, 7, r3_##S.w) \
        float di_##S = (d_##S > 0) ? 1.f / (float)d_##S : 0.f; \
        uint4 pw0_##S[8]; \
        if (BF16G) { \
            const unsigned short* xbs_ = (const unsigned short*)xb; \
            long rb_ = (long)b_##S * NN; \
            pw0_##S[0] = *(const uint4*)(xbs_ + (rb_ + idxl_##S[0]) * NC + c8); \
            pw0_##S[1] = *(const uint4*)(xbs_ + (rb_ + idxl_##S[1]) * NC + c8); \
            pw0_##S[2] = *(const uint4*)(xbs_ + (rb_ + idxl_##S[2]) * NC + c8); \
            pw0_##S[3] = *(const uint4*)(xbs_ + (rb_ + idxl_##S[3]) * NC + c8); \
            pw0_##S[4] = *(const uint4*)(xbs_ + (rb_ + idxl_##S[4]) * NC + c8); \
            pw0_##S[5] = *(const uint4*)(xbs_ + (rb_ + idxl_##S[5]) * NC + c8); \
            pw0_##S[6] = *(const uint4*)(xbs_ + (rb_ + idxl_##S[6]) * NC + c8); \
            pw0_##S[7] = *(const uint4*)(xbs_ + (rb_ + idxl_##S[7]) * NC + c8); \
        }

    // declarations (function scope) and assignment-only loads, separated so a
    // load can be issued inside a nested block (R12 compile-fix).
    #define Y_DECL(S) \
        float4 yn0_##S, yn1_##S, ya0_##S, ya1_##S; \
        float yn8_##S, ya8_##S;

    #define Y_LOAD(S) { \
        const float* ynp = y + (long)(node0_##S + ln) * YS; \
        const float* yap = y + ((long)b_##S * NN + ((a_##S > 0) ? a_##S - 1 : 0)) * YS; \
        yn0_##S = *(const float4*)ynp; \
        yn1_##S = *(const float4*)(ynp + 4); \
        yn8_##S = ynp[8]; \
        ya0_##S = *(const float4*)yap; \
        ya1_##S = *(const float4*)(yap + 4); \
        ya8_##S = yap[8]; \
    }

    // softmax -> q' (softmax * deg_inv) into own S' row; then intra-wave fence
    #define SOFTMAX_Q(S) { \
        float sel = (a_##S > 0) ? 1.f : 0.f; \
        float l[NM]; \
        l[0] = yn0_##S.x - sel * ya0_##S.x + cv[0]; \
        l[1] = yn0_##S.y - sel * ya0_##S.y + cv[1]; \
        l[2] = yn0_##S.z - sel * ya0_##S.z + cv[2]; \
        l[3] = yn0_##S.w - sel * ya0_##S.w + cv[3]; \
        l[4] = yn1_##S.x - sel * ya1_##S.x + cv[4]; \
        l[5] = yn1_##S.y - sel * ya1_##S.y + cv[5]; \
        l[6] = yn1_##S.z - sel * ya1_##S.z + cv[6]; \
        l[7] = yn1_##S.w - sel * ya1_##S.w + cv[7]; \
        l[8] = yn8_##S   - sel * ya8_##S   + cv[8]; \
        float mx = l[0]; \
        _Pragma("unroll") \
        for (int m = 1; m < NM; m++) mx = fmaxf(mx, l[m]); \
        float e[NM]; float sum = 0.f; \
        _Pragma("unroll") \
        for (int m = 0; m < NM; m++) { e[m] = __expf(l[m] - mx); sum += e[m]; } \
        float qs = ((a_##S > 0) ? (1.f / sum) : 0.f) * di_##S; \
        _Pragma("unroll") \
        for (int m = 0; m < NM; m++) qb_[k * 12 + m] = e[m] * qs; \
    } \
    asm volatile("s_waitcnt lgkmcnt(0)" ::: "memory"); \
    __builtin_amdgcn_sched_barrier(0);

    #define ACC_ALL(P0, P1, P2, P3, KK2) {                                    \
        const float* qr = qb_ + (KK2) * 12;                                   \
        float4 qa = *(const float4*)qr;                                       \
        float4 qb = *(const float4*)(qr + 4);                                 \
        float  q8 = qr[8];                                                    \
        f32x2 qq;                                                             \
        qq=(f32x2){qa.x,qa.x}; s2[0][0]+=qq*P0; s2[0][1]+=qq*P1; s2[0][2]+=qq*P2; s2[0][3]+=qq*P3; \
        qq=(f32x2){qa.y,qa.y}; s2[1][0]+=qq*P0; s2[1][1]+=qq*P1; s2[1][2]+=qq*P2; s2[1][3]+=qq*P3; \
        qq=(f32x2){qa.z,qa.z}; s2[2][0]+=qq*P0; s2[2][1]+=qq*P1; s2[2][2]+=qq*P2; s2[2][3]+=qq*P3; \
        qq=(f32x2){qa.w,qa.w}; s2[3][0]+=qq*P0; s2[3][1]+=qq*P1; s2[3][2]+=qq*P2; s2[3][3]+=qq*P3; \
        qq=(f32x2){qb.x,qb.x}; s2[4][0]+=qq*P0; s2[4][1]+=qq*P1; s2[4][2]+=qq*P2; s2[4][3]+=qq*P3; \
        qq=(f32x2){qb.y,qb.y}; s2[5][0]+=qq*P0; s2[5][1]+=qq*P1; s2[5][2]+=qq*P2; s2[5][3]+=qq*P3; \
        qq=(f32x2){qb.z,qb.z}; s2[6][0]+=qq*P0; s2[6][1]+=qq*P1; s2[6][2]+=qq*P2; s2[6][3]+=qq*P3; \
        qq=(f32x2){qb.w,qb.w}; s2[7][0]+=qq*P0; s2[7][1]+=qq*P1; s2[7][2]+=qq*P2; s2[7][3]+=qq*P3; \
        qq=(f32x2){q8,q8};     s2[8][0]+=qq*P0; s2[8][1]+=qq*P1; s2[8][2]+=qq*P2; s2[8][3]+=qq*P3; }

    // zero s2, batch-1 gather issue, 16 ACC_ALLs, S' pack (R11 layout)
    #define ACC_PACK(S) { \
        _Pragma("unroll") \
        for (int m = 0; m < NM; m++) { \
            _Pragma("unroll") \
            for (int j = 0; j < 4; j++) s2[m][j] = (f32x2){0.f, 0.f}; \
        } \
        if (BF16G) { \
            const unsigned short* xbs_ = (const unsigned short*)xb; \
            long rb_ = (long)b_##S * NN; \
            uint4 pw1[8]; \
            pw1[0] = *(const uint4*)(xbs_ + (rb_ + idxh_##S[0]) * NC + c8); \
            pw1[1] = *(const uint4*)(xbs_ + (rb_ + idxh_##S[1]) * NC + c8); \
            pw1[2] = *(const uint4*)(xbs_ + (rb_ + idxh_##S[2]) * NC + c8); \
            pw1[3] = *(const uint4*)(xbs_ + (rb_ + idxh_##S[3]) * NC + c8); \
            pw1[4] = *(const uint4*)(xbs_ + (rb_ + idxh_##S[4]) * NC + c8); \
            pw1[5] = *(const uint4*)(xbs_ + (rb_ + idxh_##S[5]) * NC + c8); \
            pw1[6] = *(const uint4*)(xbs_ + (rb_ + idxh_##S[6]) * NC + c8); \
            pw1[7] = *(const uint4*)(xbs_ + (rb_ + idxh_##S[7]) * NC + c8); \
            _Pragma("unroll") \
            for (int j = 0; j < 8; j++) { \
                f32x2 p0 = bfpair(pw0_##S[j].x), p1 = bfpair(pw0_##S[j].y); \
                f32x2 p2 = bfpair(pw0_##S[j].z), p3 = bfpair(pw0_##S[j].w); \
                ACC_ALL(p0, p1, p2, p3, j) \
            } \
            _Pragma("unroll") \
            for (int j = 0; j < 8; j++) { \
                f32x2 p0 = bfpair(pw1[j].x), p1 = bfpair(pw1[j].y); \
                f32x2 p2 = bfpair(pw1[j].z), p3 = bfpair(pw1[j].w); \
                ACC_ALL(p0, p1, p2, p3, 8 + j) \
            } \
        } else { \
            long rb_ = (long)b_##S * NN; \
            _Pragma("unroll") \
            for (int j = 0; j < 8; j++) { \
                const float* px = x + (rb_ + idxl_##S[j]) * NC + c8; \
                float4 fa = *(const float4*)px; \
                float4 fb = *(const float4*)(px + 4); \
                f32x2 p0 = (f32x2){fa.x, fa.y}, p1 = (f32x2){fa.z, fa.w}; \
                f32x2 p2 = (f32x2){fb.x, fb.y}, p3 = (f32x2){fb.z, fb.w}; \
                ACC_ALL(p0, p1, p2, p3, j) \
            } \
            _Pragma("unroll") \
            for (int j = 0; j < 8; j++) { \
                const float* px = x + (rb_ + idxh_##S[j]) * NC + c8; \
                float4 fa = *(const float4*)px; \
                float4 fb = *(const float4*)(px + 4); \
                f32x2 p0 = (f32x2){fa.x, fa.y}, p1 = (f32x2){fa.z, fa.w}; \
                f32x2 p2 = (f32x2){fb.x, fb.y}, p3 = (f32x2){fb.z, fb.w}; \
                ACC_ALL(p0, p1, p2, p3, 8 + j) \
            } \
        } \
        _Pragma("unroll") \
        for (int m = 0; m < NM; m++) { \
            u16x8 ov; \
            _Pragma("unroll") \
            for (int j = 0; j < 4; j++) { \
                union { unsigned short h; __hip_bfloat16 bb; } c0_, c1_; \
                c0_.bb = __float2bfloat16(s2[m][j][0]); \
                c1_.bb = __float2bfloat16(s2[m][j][1]); \
                ov[j * 2]     = c0_.h; \
                ov[j * 2 + 1] = c1_.h; \
            } \
            int g = m * 16 + k; \
            int gs = g ^ (ln & 7); \
            *(u16x8*)(&s_S[ln * KK + gs * 8]) = ov; \
        } \
    }

    // phase B (R11 verbatim; kc=0 uses prefetched pf0/pf1); __VA_ARGS__ runs
    // between the kc-loop and the epilogue (used to issue tile1's y loads).
    #define B_PHASE(S, ...) { \
        f32x4 acc0 = (f32x4){0.f, 0.f, 0.f, 0.f}; \
        f32x4 acc1 = (f32x4){0.f, 0.f, 0.f, 0.f}; \
        { \
            int gs = quad ^ (lr & 7); \
            bf16x8 a0 = *(const bf16x8*)(&s_S[lr * KK + gs * 8]); \
            acc0 = __builtin_amdgcn_mfma_f32_16x16x32_bf16(a0, pf0, acc0, 0, 0, 0); \
            acc1 = __builtin_amdgcn_mfma_f32_16x16x32_bf16(a0, pf1, acc1, 0, 0, 0); \
        } \
        _Pragma("unroll 7") \
        for (int kc = 1; kc < NKC; kc++) { \
            int g = kc * 4 + quad; \
            int gs = g ^ (lr & 7); \
            bf16x8 a0 = *(const bf16x8*)(&s_S[lr * KK + gs * 8]); \
            bf16x8 bf0 = *(const bf16x8*)(wg + ((kc * 128) + wave * 16 + lr) * 32 + quad * 8); \
            bf16x8 bf1 = *(const bf16x8*)(wg + ((kc * 128) + (wave + 4) * 16 + lr) * 32 + quad * 8); \
            acc0 = __builtin_amdgcn_mfma_f32_16x16x32_bf16(a0, bf0, acc0, 0, 0, 0); \
            acc1 = __builtin_amdgcn_mfma_f32_16x16x32_bf16(a0, bf1, acc1, 0, 0, 0); \
        } \
        __VA_ARGS__ \
        int rbase = node0_##S + quad * 4; \
        _Pragma("unroll") \
        for (int r = 0; r < 4; r++) { \
            out[(long)(rbase + r) * NO + col0] = acc0[r] + bb0; \
            out[(long)(rbase + r) * NO + col1] = acc1[r] + bb1; \
        } \
    }

    // ---------------- pipeline ----------------
    DECL_TILE(0)
    DECL_TILE(1)
    f32x2 s2[NM][4];

    // tile 0 front end
    A_EARLY(0)
    Y_DECL(0)
    Y_LOAD(0)
    SOFTMAX_Q(0)
    ACC_PACK(0)

    // tile 1 front end issue (registers only; flies under bar3 + B(0))
    A_EARLY(1)
    Y_DECL(1)

    // tile-invariant phase-B prefetch
    int wave = tid >> 6;
    int lane = tid & 63;
    int lr = lane & 15;
    int quad = lane >> 4;
    const short* wg = reinterpret_cast<const short*>(Wg);
    int col0 = wave * 16 + lr;
    int col1 = col0 + 64;
    float bb0 = bv[col0];
    float bb1 = bv[col1];
    bf16x8 pf0 = *(const bf16x8*)(wg + (wave * 16 + lr) * 32 + quad * 8);
    bf16x8 pf1 = *(const bf16x8*)(wg + ((wave + 4) * 16 + lr) * 32 + quad * 8);

    __syncthreads();                                   // bar3: S'(0) ready

    B_PHASE(0, Y_LOAD(1))                              // y(1) issues under epilogue

    __syncthreads();                                   // bar4: B(0) done, S' free

    SOFTMAX_Q(1)
    ACC_PACK(1)

    __syncthreads();                                   // bar5: S'(1) ready

    B_PHASE(1, ;)

    #undef B_PHASE
    #undef ACC_PACK
    #undef ACC_ALL
    #undef SOFTMAX_Q
    #undef Y_LOAD
    #undef Y_DECL
    #undef A_EARLY
    #undef PUTV
    #undef DECL_TILE
}

extern "C" void kernel_launch(void* const* d_in, const int* in_sizes, int n_in,
                              void* d_out, int out_size, void* d_ws, size_t ws_size,
                              hipStream_t stream) {
    const float* x   = (const float*)d_in[0];   // (B,N,C)
    const int*   adj = (const int*)  d_in[1];   // (N,K)
    const float* W   = (const float*)d_in[2];   // (M,O,C)
    const float* bv  = (const float*)d_in[3];   // (O,)
    const float* u   = (const float*)d_in[4];   // (M,C)
    const float* cv  = (const float*)d_in[5];   // (M,)
    float* out = (float*)d_out;

    char* ws = (char*)d_ws;
    float* y = (float*)ws;                                     // 1,920,000 B
    __hip_bfloat16* Wg = (__hip_bfloat16*)(ws + 1920000);      //   294,912 B
    __hip_bfloat16* xb = (__hip_bfloat16*)(ws + 2214912);      // 10,240,000 B
    bool use_xb = (ws_size >= (size_t)12454912);

    prep_kernel<<<YB + 576, 256, 0, stream>>>(x, u, W, y, use_xb ? xb : nullptr, Wg,
                                              use_xb ? 1 : 0);
    if (use_xb)
        fused_kernel<true><<<NR / (NPB * NTL), 256, 0, stream>>>(x, xb, adj, y, cv, Wg, bv, out);
    else
        fused_kernel<false><<<NR / (NPB * NTL), 256, 0, stream>>>(x, xb, adj, y, cv, Wg, bv, out);
}

// Round 15
// 138.143 us; speedup vs baseline: 1.7102x; 1.0630x over previous
//
#include <hip/hip_runtime.h>
#include <hip/hip_bf16.h>

#define NB 2
#define NN 20000
#define NKN 16          // neighbors per node
#define NC 128          // C_IN
#define NM 9            // M kernels
#define NO 128          // C_OUT
#define NR (NB*NN)      // 40000 rows
#define KK (NM*NC)      // 1152 GEMM reduce dim
#define NKC (KK/32)     // 36 K-chunks of 32
#define NPB 16          // nodes per fused block
#define YS 12           // padded y row stride (floats)
#define YB (NR/64)      // ycalc blocks = 625

typedef short bf16x8 __attribute__((ext_vector_type(8)));
typedef float f32x4 __attribute__((ext_vector_type(4)));
typedef float f32x2 __attribute__((ext_vector_type(2)));
typedef unsigned short u16x8 __attribute__((ext_vector_type(8)));

__device__ inline f32x2 bfpair(unsigned int w) {   // [lo16, hi16] bf16 -> float2
    union { unsigned int u; float f; } lo, hi;
    lo.u = w << 16; hi.u = w & 0xFFFF0000u;
    return (f32x2){lo.f, hi.f};
}

// ---------------- Kernel 1: prep (R9 version: coalesced Wg-repack reads) ----
__global__ __launch_bounds__(256) void prep_kernel(const float* __restrict__ x,
                                                   const float* __restrict__ u,
                                                   const float* __restrict__ W,
                                                   float* __restrict__ y,
                                                   __hip_bfloat16* __restrict__ xb,
                                                   __hip_bfloat16* __restrict__ Wg,
                                                   int use_xb) {
    int tid = threadIdx.x;
    if (blockIdx.x < YB) {
        int wave = tid >> 6, lane = tid & 63;
        int lr = lane & 15, quad = lane >> 4;
        int node0 = blockIdx.x * 64 + wave * 16;
        long xbase = (long)(node0 + lr) * NC;

        bf16x8 afr[4];
        #pragma unroll
        for (int kc = 0; kc < 4; kc++) {
            const float* px = x + xbase + kc * 32 + quad * 8;
            float4 a0 = *(const float4*)px;
            float4 a1 = *(const float4*)(px + 4);
            union { bf16x8 v; unsigned short s[8]; __hip_bfloat16 h[8]; } af;
            af.h[0] = __float2bfloat16(a0.x); af.h[1] = __float2bfloat16(a0.y);
            af.h[2] = __float2bfloat16(a0.z); af.h[3] = __float2bfloat16(a0.w);
            af.h[4] = __float2bfloat16(a1.x); af.h[5] = __float2bfloat16(a1.y);
            af.h[6] = __float2bfloat16(a1.z); af.h[7] = __float2bfloat16(a1.w);
            afr[kc] = af.v;
            if (use_xb)
                *(u16x8*)((unsigned short*)xb + xbase + kc * 32 + quad * 8) =
                    *(u16x8*)&af.v;
        }
        int cs = (lr < NM) ? lr : 0;
        float fz = (lr < NM) ? 1.f : 0.f;
        f32x4 acc = (f32x4){0.f, 0.f, 0.f, 0.f};
        #pragma unroll
        for (int kc = 0; kc < 4; kc++) {
            const float* pu = u + cs * NC + kc * 32 + quad * 8;
            float4 b0 = *(const float4*)pu;
            float4 b1 = *(const float4*)(pu + 4);
            union { bf16x8 v; __hip_bfloat16 h[8]; } bf;
            bf.h[0] = __float2bfloat16(b0.x * fz); bf.h[1] = __float2bfloat16(b0.y * fz);
            bf.h[2] = __float2bfloat16(b0.z * fz); bf.h[3] = __float2bfloat16(b0.w * fz);
            bf.h[4] = __float2bfloat16(b1.x * fz); bf.h[5] = __float2bfloat16(b1.y * fz);
            bf.h[6] = __float2bfloat16(b1.z * fz); bf.h[7] = __float2bfloat16(b1.w * fz);
            acc = __builtin_amdgcn_mfma_f32_16x16x32_bf16(afr[kc], bf.v, acc, 0, 0, 0);
        }
        if (lr < NM) {
            #pragma unroll
            for (int r = 0; r < 4; r++)
                y[(long)(node0 + quad * 4 + r) * YS + lr] = acc[r];
        }
    } else {
        // Wg repack, read-coalesced (R9's prep win).
        int t = (blockIdx.x - YB) * 256 + tid;   // t < 9*128*128
        int c = t & 127;
        int o = (t >> 7) & 127;
        int m = t >> 14;
        int kk = m * 128 + c;
        float v = W[m * 16384 + o * 128 + c];
        Wg[((kk >> 5) * 128 + o) * 32 + (kk & 31)] = __float2bfloat16(v);
    }
}

// ---------------- Kernel 2: fused (R11: best verified, 63.5 µs) ----------
// 16 nodes/block, 256 threads (4 waves), LDS 36,864 B -> 4 blocks/CU.
// q lives in each node's own S' row (first 896 B, staggered (ln&7)<<4);
// S'-pack only clobbers the same wave's q -> single block barrier (bar3).
// __expf softmax, di folded into q, XOR-swizzled S', phase-B kc=0 prefetch.
template<bool BF16G>
__global__ __launch_bounds__(256, 4) void fused_kernel(const float* __restrict__ x,
                                                       const __hip_bfloat16* __restrict__ xb,
                                                       const int* __restrict__ adj,
                                                       const float* __restrict__ y,
                                                       const float* __restrict__ cv,
                                                       const __hip_bfloat16* __restrict__ Wg,
                                                       const float* __restrict__ bv,
                                                       float* __restrict__ out) {
    __shared__ __align__(16) short s_S[NPB * KK];          // 36,864 B total LDS

    int tid = threadIdx.x;
    int node0 = blockIdx.x * NPB;
    int b = node0 / NN;
    int n0 = node0 - b * NN;
    int ln = tid >> 4, k = tid & 15;                       // 256 = 16 nodes x 16 edges

    // node ln's q lives in its own S' row (bytes [ln*2304, +896) incl. stagger)
    float* qb_ = (float*)((char*)s_S + ln * (KK * 2) + ((ln & 7) << 4));

    // ---- A1: own edge + full adj row (registers, no barrier) ----
    const int* arow = adj + (n0 + ln) * NKN;
    int a = arow[k];
    int4 r0 = *(const int4*)arow;
    int4 r1 = *(const int4*)(arow + 4);
    int4 r2 = *(const int4*)(arow + 8);
    int4 r3 = *(const int4*)(arow + 12);

    const float* yn = y + (long)(node0 + ln) * YS;
    const float* ya = y + (long)(b * NN + ((a > 0) ? a - 1 : 0)) * YS;
    float4 yn0 = *(const float4*)yn;
    float4 yn1 = *(const float4*)(yn + 4);
    float  yn8 = yn[8];
    float4 ya0 = *(const float4*)ya;
    float4 ya1 = *(const float4*)(ya + 4);
    float  ya8 = ya[8];

    // ---- idx/deg from registers; issue gather batch 0 ----
    int idx[NKN]; int d = 0;
    #define PUT(J, V) { int aa = (V); d += (aa > 0); idx[J] = (aa > 0) ? aa - 1 : 0; }
    PUT(0, r0.x)  PUT(1, r0.y)  PUT(2, r0.z)  PUT(3, r0.w)
    PUT(4, r1.x)  PUT(5, r1.y)  PUT(6, r1.z)  PUT(7, r1.w)
    PUT(8, r2.x)  PUT(9, r2.y)  PUT(10, r2.z) PUT(11, r2.w)
    PUT(12, r3.x) PUT(13, r3.y) PUT(14, r3.z) PUT(15, r3.w)
    #undef PUT
    float di = (d > 0) ? 1.f / (float)d : 0.f;

    int c8 = k << 3;
    uint4 pw0[8];
    if (BF16G) {
        #pragma unroll
        for (int j = 0; j < 8; j++)
            pw0[j] = *(const uint4*)((const unsigned short*)xb +
                                     (long)(b * NN + idx[j]) * NC + c8);
    }

    // ---- A2: softmax (native exp); q' = softmax * deg_inv -> own S' row ----
    {
        float sel = (a > 0) ? 1.f : 0.f;
        float l[NM];
        l[0] = yn0.x - sel * ya0.x + cv[0];
        l[1] = yn0.y - sel * ya0.y + cv[1];
        l[2] = yn0.z - sel * ya0.z + cv[2];
        l[3] = yn0.w - sel * ya0.w + cv[3];
        l[4] = yn1.x - sel * ya1.x + cv[4];
        l[5] = yn1.y - sel * ya1.y + cv[5];
        l[6] = yn1.z - sel * ya1.z + cv[6];
        l[7] = yn1.w - sel * ya1.w + cv[7];
        l[8] = yn8   - sel * ya8   + cv[8];
        float mx = l[0];
        #pragma unroll
        for (int m = 1; m < NM; m++) mx = fmaxf(mx, l[m]);
        float e[NM]; float sum = 0.f;
        #pragma unroll
        for (int m = 0; m < NM; m++) { e[m] = __expf(l[m] - mx); sum += e[m]; }
        float qs = ((a > 0) ? (1.f / sum) : 0.f) * di;     // deg_inv folded in
        #pragma unroll
        for (int m = 0; m < NM; m++) qb_[k * 12 + m] = e[m] * qs;
    }
    // intra-wave q exchange: node ln's 16 threads share one wave.
    asm volatile("s_waitcnt lgkmcnt(0)" ::: "memory");
    __builtin_amdgcn_sched_barrier(0);

    // ---- A3: issue batch 1, then accumulate both batches (f32x2 packed FMA) ----
    f32x2 s2[NM][4];
    #pragma unroll
    for (int m = 0; m < NM; m++)
        #pragma unroll
        for (int j = 0; j < 4; j++) s2[m][j] = (f32x2){0.f, 0.f};

    #define ACC_ALL(P0, P1, P2, P3, KK2) {                                    \
        const float* qr = qb_ + (KK2) * 12;                                   \
        float4 qa = *(const float4*)qr;                                       \
        float4 qb = *(const float4*)(qr + 4);                                 \
        float  q8 = qr[8];                                                    \
        f32x2 qq;                                                             \
        qq=(f32x2){qa.x,qa.x}; s2[0][0]+=qq*P0; s2[0][1]+=qq*P1; s2[0][2]+=qq*P2; s2[0][3]+=qq*P3; \
        qq=(f32x2){qa.y,qa.y}; s2[1][0]+=qq*P0; s2[1][1]+=qq*P1; s2[1][2]+=qq*P2; s2[1][3]+=qq*P3; \
        qq=(f32x2){qa.z,qa.z}; s2[2][0]+=qq*P0; s2[2][1]+=qq*P1; s2[2][2]+=qq*P2; s2[2][3]+=qq*P3; \
        qq=(f32x2){qa.w,qa.w}; s2[3][0]+=qq*P0; s2[3][1]+=qq*P1; s2[3][2]+=qq*P2; s2[3][3]+=qq*P3; \
        qq=(f32x2){qb.x,qb.x}; s2[4][0]+=qq*P0; s2[4][1]+=qq*P1; s2[4][2]+=qq*P2; s2[4][3]+=qq*P3; \
        qq=(f32x2){qb.y,qb.y}; s2[5][0]+=qq*P0; s2[5][1]+=qq*P1; s2[5][2]+=qq*P2; s2[5][3]+=qq*P3; \
        qq=(f32x2){qb.z,qb.z}; s2[6][0]+=qq*P0; s2[6][1]+=qq*P1; s2[6][2]+=qq*P2; s2[6][3]+=qq*P3; \
        qq=(f32x2){qb.w,qb.w}; s2[7][0]+=qq*P0; s2[7][1]+=qq*P1; s2[7][2]+=qq*P2; s2[7][3]+=qq*P3; \
        qq=(f32x2){q8,q8};     s2[8][0]+=qq*P0; s2[8][1]+=qq*P1; s2[8][2]+=qq*P2; s2[8][3]+=qq*P3; }

    if (BF16G) {
        uint4 pw1[8];
        #pragma unroll
        for (int j = 0; j < 8; j++)
            pw1[j] = *(const uint4*)((const unsigned short*)xb +
                                     (long)(b * NN + idx[8 + j]) * NC + c8);
        #pragma unroll
        for (int j = 0; j < 8; j++) {
            f32x2 p0 = bfpair(pw0[j].x), p1 = bfpair(pw0[j].y);
            f32x2 p2 = bfpair(pw0[j].z), p3 = bfpair(pw0[j].w);
            ACC_ALL(p0, p1, p2, p3, j)
        }
        #pragma unroll
        for (int j = 0; j < 8; j++) {
            f32x2 p0 = bfpair(pw1[j].x), p1 = bfpair(pw1[j].y);
            f32x2 p2 = bfpair(pw1[j].z), p3 = bfpair(pw1[j].w);
            ACC_ALL(p0, p1, p2, p3, 8 + j)
        }
    } else {
        #pragma unroll
        for (int g = 0; g < NKN / 4; g++) {
            float4 fa[4], fb[4];
            #pragma unroll
            for (int j = 0; j < 4; j++) {
                const float* px = x + (long)(b * NN + idx[g * 4 + j]) * NC + c8;
                fa[j] = *(const float4*)px;
                fb[j] = *(const float4*)(px + 4);
            }
            #pragma unroll
            for (int j = 0; j < 4; j++) {
                f32x2 p0 = (f32x2){fa[j].x, fa[j].y}, p1 = (f32x2){fa[j].z, fa[j].w};
                f32x2 p2 = (f32x2){fb[j].x, fb[j].y}, p3 = (f32x2){fb[j].z, fb[j].w};
                ACC_ALL(p0, p1, p2, p3, g * 4 + j)
            }
        }
    }
    #undef ACC_ALL

    // ---- pack + write S' into own row, XOR-swizzled. No barrier needed:
    // the only LDS bytes clobbered are node ln's own q, whose readers are
    // this same wave, and per-wave DS ops complete in order. ----
    #pragma unroll
    for (int m = 0; m < NM; m++) {
        u16x8 ov;
        #pragma unroll
        for (int j = 0; j < 4; j++) {
            union { unsigned short h; __hip_bfloat16 bb; } c0, c1;
            c0.bb = __float2bfloat16(s2[m][j][0]);
            c1.bb = __float2bfloat16(s2[m][j][1]);
            ov[j * 2]     = c0.h;
            ov[j * 2 + 1] = c1.h;
        }
        int g = m * 16 + k;                                // 16B granule index in row
        int gs = g ^ (ln & 7);                             // XOR swizzle
        *(u16x8*)(&s_S[ln * KK + gs * 8]) = ov;
    }

    // ---- phase-B prefetch (independent of S'; hoisted above the barrier) ----
    int wave = tid >> 6;                                   // 0..3
    int lane = tid & 63;
    int lr = lane & 15;
    int quad = lane >> 4;
    const short* wg = reinterpret_cast<const short*>(Wg);
    int col0 = wave * 16 + lr;
    int col1 = col0 + 64;
    float bb0 = bv[col0];
    float bb1 = bv[col1];
    bf16x8 pf0 = *(const bf16x8*)(wg + (wave * 16 + lr) * 32 + quad * 8);
    bf16x8 pf1 = *(const bf16x8*)(wg + ((wave + 4) * 16 + lr) * 32 + quad * 8);

    __syncthreads();                                       // bar3: S' ready

    // -------- phase B: GEMM 16x1152 @ 1152x128; wave = col-tiles {w, w+4} -------
    f32x4 acc0 = (f32x4){0.f, 0.f, 0.f, 0.f};              // cols wave*16..+15
    f32x4 acc1 = (f32x4){0.f, 0.f, 0.f, 0.f};              // cols 64+wave*16..+15

    {   // kc = 0 with prefetched B-fragments
        int gs = quad ^ (lr & 7);
        bf16x8 a0 = *(const bf16x8*)(&s_S[lr * KK + gs * 8]);
        acc0 = __builtin_amdgcn_mfma_f32_16x16x32_bf16(a0, pf0, acc0, 0, 0, 0);
        acc1 = __builtin_amdgcn_mfma_f32_16x16x32_bf16(a0, pf1, acc1, 0, 0, 0);
    }
    #pragma unroll 7
    for (int kc = 1; kc < NKC; kc++) {
        int g = kc * 4 + quad;
        int gs = g ^ (lr & 7);
        bf16x8 a0 = *(const bf16x8*)(&s_S[lr * KK + gs * 8]);
        bf16x8 bf0 = *(const bf16x8*)(wg + ((kc * 128) + wave * 16 + lr) * 32 + quad * 8);
        bf16x8 bf1 = *(const bf16x8*)(wg + ((kc * 128) + (wave + 4) * 16 + lr) * 32 + quad * 8);
        acc0 = __builtin_amdgcn_mfma_f32_16x16x32_bf16(a0, bf0, acc0, 0, 0, 0);
        acc1 = __builtin_amdgcn_mfma_f32_16x16x32_bf16(a0, bf1, acc1, 0, 0, 0);
    }

    // epilogue: D row = quad*4 + r; cols wave*16+lr and 64+wave*16+lr
    int rbase = node0 + quad * 4;
    #pragma unroll
    for (int r = 0; r < 4; r++) {
        out[(long)(rbase + r) * NO + col0] = acc0[r] + bb0;
        out[(long)(rbase + r) * NO + col1] = acc1[r] + bb1;
    }
}

extern "C" void kernel_launch(void* const* d_in, const int* in_sizes, int n_in,
                              void* d_out, int out_size, void* d_ws, size_t ws_size,
                              hipStream_t stream) {
    const float* x   = (const float*)d_in[0];   // (B,N,C)
    const int*   adj = (const int*)  d_in[1];   // (N,K)
    const float* W   = (const float*)d_in[2];   // (M,O,C)
    const float* bv  = (const float*)d_in[3];   // (O,)
    const float* u   = (const float*)d_in[4];   // (M,C)
    const float* cv  = (const float*)d_in[5];   // (M,)
    float* out = (float*)d_out;

    char* ws = (char*)d_ws;
    float* y = (float*)ws;                                     // 1,920,000 B
    __hip_bfloat16* Wg = (__hip_bfloat16*)(ws + 1920000);      //   294,912 B
    __hip_bfloat16* xb = (__hip_bfloat16*)(ws + 2214912);      // 10,240,000 B
    bool use_xb = (ws_size >= (size_t)12454912);

    prep_kernel<<<YB + 576, 256, 0, stream>>>(x, u, W, y, use_xb ? xb : nullptr, Wg,
                                              use_xb ? 1 : 0);
    if (use_xb)
        fused_kernel<true><<<NR / NPB, 256, 0, stream>>>(x, xb, adj, y, cv, Wg, bv, out);
    else
        fused_kernel<false><<<NR / NPB, 256, 0, stream>>>(x, xb, adj, y, cv, Wg, bv, out);
}